// Round 10
// baseline (90.105 us; speedup 1.0000x reference)
//
#include <hip/hip_runtime.h>
#include <hip/hip_bf16.h>
#include <cstdint>

// EdgeMLP R10: wave-pair hidden-split. Pair (w0,w1) handles 32 edges/iter;
// each wave computes 64 of 128 hidden for both 16-edge sub-tiles ->
// W1 LDS reads halved per edge (1 b128/edge) with acc still 32 VGPRs.
// Layer-2 partials combined via 1KB parity-double-buffered LDS + 1 barrier/iter.
// ws: [hb: nNodes*64 bf16][w1tab: 16384 bf16][w2tab: 2048 bf16]

constexpr int EMB = 64;
constexpr int HID = 128;

typedef short s16x8 __attribute__((ext_vector_type(8)));
typedef float f32x4 __attribute__((ext_vector_type(4)));

__device__ __forceinline__ unsigned short f2bf(float x) {
    unsigned u = __float_as_uint(x);
    u = (u + 0x7fffu + ((u >> 16) & 1u)) >> 16;   // RNE
    return (unsigned short)u;
}

// ---- prep 1: h fp32 -> bf16 ----
__global__ void conv_h_kernel(const float* __restrict__ h,
                              unsigned short* __restrict__ hb, int n8) {
    const int i = blockIdx.x * blockDim.x + threadIdx.x;
    if (i >= n8) return;
    const float* p = h + (size_t)i * 8;
    float4 a = *reinterpret_cast<const float4*>(p);
    float4 b = *reinterpret_cast<const float4*>(p + 4);
    unsigned short r[8];
    r[0] = f2bf(a.x); r[1] = f2bf(a.y); r[2] = f2bf(a.z); r[3] = f2bf(a.w);
    r[4] = f2bf(b.x); r[5] = f2bf(b.y); r[6] = f2bf(b.z); r[7] = f2bf(b.w);
    *reinterpret_cast<uint4*>(hb + (size_t)i * 8) = *reinterpret_cast<const uint4*>(r);
}

// ---- prep 2: W1 + W2 fragment tables (validated layouts) ----
__global__ void pack_tabs(const float* __restrict__ W1,
                          const float* __restrict__ W2,
                          unsigned short* __restrict__ tab) {
    const int i = blockIdx.x * blockDim.x + threadIdx.x;
    if (i < 16384) {
        const int j = i & 7, lane = (i >> 3) & 63, ks = (i >> 9) & 3, nt = i >> 11;
        const int k = ks * 32 + (lane >> 4) * 8 + j;
        const int n = nt * 16 + (lane & 15);
        tab[i] = f2bf(W1[(size_t)k * HID + n]);
    } else if (i < 16384 + 2048) {
        const int q = i - 16384;
        const int j = q & 7, lane = (q >> 3) & 63, ks = q >> 9;
        const int tc = lane & 15, bq = lane >> 4;
        const int mt = ks * 2 + (j >> 2), r = j & 3;
        tab[i] = (tc < 2) ? f2bf(W2[(mt * 16 + bq * 4 + r) * 2 + tc])
                          : (unsigned short)0;
    }
}

// ---- main ----
__global__ __launch_bounds__(256, 2)
void edge_mlp_r10(const unsigned short* __restrict__ hb,
                  const unsigned short* __restrict__ tab,
                  const int* __restrict__ eidx,
                  const float* __restrict__ b1,
                  const float* __restrict__ b2,
                  float* __restrict__ out, int E, int nTiles)
{
    __shared__ uint4 w1s[2048];             // 32 KB W1 fragments
    __shared__ float b1s[128];              // 512 B
    __shared__ float2 pbuf[2][2][2][16];    // [parity][pair][subtile][lane] 1 KB
    {
        const uint4* src = reinterpret_cast<const uint4*>(tab);
        #pragma unroll
        for (int r = 0; r < 8; ++r)
            w1s[r * 256 + threadIdx.x] = src[r * 256 + threadIdx.x];
        if (threadIdx.x < 128) b1s[threadIdx.x] = b1[threadIdx.x];
    }
    __syncthreads();

    const int t = threadIdx.x, wid = t >> 6, lane = t & 63;
    const int tc = lane & 15, bq = lane >> 4;
    const int pairId = wid >> 1, half = wid & 1;

    const s16x8* wf = reinterpret_cast<const s16x8*>(w1s) + lane;  // + (ntG*4+ks)*64
    const float* b1v = b1s + half * 64 + bq * 4;                   // + nt*16

    // this wave's 2 layer-2 W2 fragments (ks2 = half*2+q), persistent in regs
    s16x8 w2f[2];
    #pragma unroll
    for (int q = 0; q < 2; ++q)
        w2f[q] = *reinterpret_cast<const s16x8*>(
            tab + 16384 + (((half * 2 + q) * 64 + lane) * 8));

    // b2 folded once: only half 0's partial carries it
    const float a20 = (half == 0 && bq == 0) ? b2[0] : 0.f;
    const float a21 = (half == 0 && bq == 0) ? b2[1] : 0.f;

    const int stride = gridDim.x * 2;
    int par = 0;
    for (int bt = blockIdx.x * 2; bt < nTiles; bt += stride, par ^= 1) {
        const int tile = bt + pairId;
        const bool active = (tile < nTiles);
        float2 oA, oB;

        if (active) {
            const int base = tile * 32;
            const int eA = min(base + tc, E - 1);
            const int eB = min(base + 16 + tc, E - 1);
            const int sA = eidx[eA], dA = eidx[E + eA];
            const int sB = eidx[eB], dB = eidx[E + eB];

            // gather both 16-edge sub-tiles (64B-contiguous per row per instr)
            s16x8 xfA[4], xfB[4];
            {
                const s16x8* ps = reinterpret_cast<const s16x8*>(hb + (size_t)sA * EMB + bq * 8);
                const s16x8* pd = reinterpret_cast<const s16x8*>(hb + (size_t)dA * EMB + bq * 8);
                xfA[0] = ps[0]; xfA[1] = ps[4]; xfA[2] = pd[0]; xfA[3] = pd[4];
                const s16x8* qs = reinterpret_cast<const s16x8*>(hb + (size_t)sB * EMB + bq * 8);
                const s16x8* qd = reinterpret_cast<const s16x8*>(hb + (size_t)dB * EMB + bq * 8);
                xfB[0] = qs[0]; xfB[1] = qs[4]; xfB[2] = qd[0]; xfB[3] = qd[4];
            }

            // layer 1: this wave's 4 nt tiles (hidden half*64..+63), both sub-tiles
            f32x4 accA[4], accB[4];
            #pragma unroll
            for (int nt = 0; nt < 4; ++nt) {
                const f32x4 ini = *reinterpret_cast<const f32x4*>(b1v + nt * 16);
                const s16x8 w = wf[((half * 4 + nt) * 4) * 64];
                accA[nt] = __builtin_amdgcn_mfma_f32_16x16x32_bf16(w, xfA[0], ini, 0, 0, 0);
                accB[nt] = __builtin_amdgcn_mfma_f32_16x16x32_bf16(w, xfB[0], ini, 0, 0, 0);
            }
            #pragma unroll
            for (int ks = 1; ks < 4; ++ks)
                #pragma unroll
                for (int nt = 0; nt < 4; ++nt) {
                    const s16x8 w = wf[((half * 4 + nt) * 4 + ks) * 64];
                    accA[nt] = __builtin_amdgcn_mfma_f32_16x16x32_bf16(w, xfA[ks], accA[nt], 0, 0, 0);
                    accB[nt] = __builtin_amdgcn_mfma_f32_16x16x32_bf16(w, xfB[ks], accB[nt], 0, 0, 0);
                }

            // layer-2 partial (this wave's ks2 pair), both sub-tiles
            #pragma unroll
            for (int st = 0; st < 2; ++st) {
                const f32x4* acc = st ? accB : accA;
                f32x4 o = {a20, a21, 0.f, 0.f};
                #pragma unroll
                for (int q = 0; q < 2; ++q) {
                    s16x8 p;
                    #pragma unroll
                    for (int jj = 0; jj < 4; ++jj) {
                        const int mt = q * 2 + (jj >> 1), r = (jj & 1) * 2;
                        float2 v = make_float2(fmaxf(acc[mt][r], 0.f),
                                               fmaxf(acc[mt][r + 1], 0.f));
                        __hip_bfloat162 bb = __float22bfloat162_rn(v);
                        reinterpret_cast<unsigned*>(&p)[jj] = *reinterpret_cast<unsigned*>(&bb);
                    }
                    o = __builtin_amdgcn_mfma_f32_16x16x32_bf16(w2f[q], p, o, 0, 0, 0);
                }
                if (st == 0) oA = make_float2(o[0], o[1]);
                else         oB = make_float2(o[0], o[1]);
            }

            if (half == 1 && lane < 16) {
                pbuf[par][pairId][0][lane] = oA;
                pbuf[par][pairId][1][lane] = oB;
            }
        }

        __syncthreads();   // block-uniform trip count; combines pair partials

        if (active && half == 0 && lane < 16) {
            const float2 qA = pbuf[par][pairId][0][lane];
            const float2 qB = pbuf[par][pairId][1][lane];
            const int base = tile * 32;
            if (base + lane < E)
                *reinterpret_cast<float2*>(out + (size_t)(base + lane) * 2) =
                    make_float2(oA.x + qA.x, oA.y + qA.y);
            if (base + 16 + lane < E)
                *reinterpret_cast<float2*>(out + (size_t)(base + 16 + lane) * 2) =
                    make_float2(oB.x + qB.x, oB.y + qB.y);
        }
    }
}

// ---- fallback (ws too small; correct but slow) ----
__global__ void edge_mlp_naive(const float* __restrict__ h, const int* __restrict__ eidx,
                               const float* __restrict__ W1, const float* __restrict__ b1,
                               const float* __restrict__ W2, const float* __restrict__ b2,
                               float* __restrict__ out, int E) {
    const int e = blockIdx.x * 256 + threadIdx.x;
    if (e >= E) return;
    const float* hs = h + (size_t)eidx[e] * EMB;
    const float* hd = h + (size_t)eidx[E + e] * EMB;
    float o0 = b2[0], o1 = b2[1];
    for (int j = 0; j < HID; ++j) {
        float a = b1[j];
        for (int k = 0; k < EMB; ++k)
            a += hs[k] * W1[(size_t)k * HID + j] + hd[k] * W1[(size_t)(k + EMB) * HID + j];
        a = fmaxf(a, 0.f);
        o0 = fmaf(a, W2[j * 2 + 0], o0);
        o1 = fmaf(a, W2[j * 2 + 1], o1);
    }
    out[(size_t)e * 2 + 0] = o0;
    out[(size_t)e * 2 + 1] = o1;
}

extern "C" void kernel_launch(void* const* d_in, const int* in_sizes, int n_in,
                              void* d_out, int out_size, void* d_ws, size_t ws_size,
                              hipStream_t stream)
{
    const float* h  = (const float*)d_in[0];
    const int*   ei = (const int*)d_in[1];
    const float* W1 = (const float*)d_in[2];
    const float* b1 = (const float*)d_in[3];
    const float* W2 = (const float*)d_in[4];
    const float* b2 = (const float*)d_in[5];
    float* out = (float*)d_out;

    const int nNodes = in_sizes[0] / EMB;
    const int E      = in_sizes[1] / 2;
    const int nTiles = (E + 31) / 32;

    const size_t hbElems = (size_t)nNodes * EMB;
    const size_t need    = hbElems * 2 + (16384 + 2048) * 2;

    if (ws_size >= need) {
        unsigned short* hb  = (unsigned short*)d_ws;
        unsigned short* tab = hb + hbElems;
        const int n8 = (int)(hbElems / 8);
        hipLaunchKernelGGL(conv_h_kernel, dim3((n8 + 255) / 256), dim3(256), 0, stream,
                           h, hb, n8);
        hipLaunchKernelGGL(pack_tabs, dim3(72), dim3(256), 0, stream, W1, W2, tab);
        hipLaunchKernelGGL(edge_mlp_r10, dim3(1024), dim3(256), 0, stream,
                           hb, tab, ei, b1, b2, out, E, nTiles);
    } else {
        hipLaunchKernelGGL(edge_mlp_naive, dim3((E + 255) / 256), dim3(256), 0, stream,
                           h, ei, W1, b1, W2, b2, out, E);
    }
}